// Round 4
// baseline (343.234 us; speedup 1.0000x reference)
//
#include <hip/hip_runtime.h>
#include <hip/hip_fp16.h>
#include <math.h>

#define NEG_SLOPE 0.01f

// ---------------- CSR build: direct global-atomic counting sort ----------------
// Replaces the 5-kernel bucketed multisplit (bkhist/scan over 100k matrix/bksplit/
// csr_build). Within-row order is arbitrary (sum is order-independent), so a simple
// countdown-cursor scatter suffices. deg/lex are 200KB => L2-resident.

// k1: per-node in-degree. ~32 atomics/address spread over 50k addresses.
__global__ void deghist_kernel(const int* __restrict__ dst, int* __restrict__ deg, int E) {
    int stride = gridDim.x * blockDim.x;
    for (int e = blockIdx.x * blockDim.x + threadIdx.x; e < E; e += stride)
        atomicAdd(&deg[dst[e]], 1);
}

// k2/k3: two-level exclusive scan over deg[0..N] (N+1 entries; deg[N]=0 pad).
// Consumers reconstruct prefix as lex[i] + par[i>>10] (scan3 stays eliminated).
__global__ void scan1_kernel(const int* __restrict__ in, int* __restrict__ local_excl,
                             int* __restrict__ partials, int n) {
    __shared__ int sm[1024];
    int i = blockIdx.x * 1024 + threadIdx.x;
    int x = (i < n) ? in[i] : 0;
    sm[threadIdx.x] = x;
    __syncthreads();
    for (int off = 1; off < 1024; off <<= 1) {
        int y = (threadIdx.x >= (unsigned)off) ? sm[threadIdx.x - off] : 0;
        __syncthreads();
        sm[threadIdx.x] += y;
        __syncthreads();
    }
    if (i < n) local_excl[i] = sm[threadIdx.x] - x;
    if (threadIdx.x == 1023) partials[blockIdx.x] = sm[1023];
}

__global__ void scan2_kernel(int* __restrict__ partials, int nchunks) {
    __shared__ int sm[1024];
    int x = (threadIdx.x < (unsigned)nchunks) ? partials[threadIdx.x] : 0;
    sm[threadIdx.x] = x;
    __syncthreads();
    for (int off = 1; off < 1024; off <<= 1) {
        int y = (threadIdx.x >= (unsigned)off) ? sm[threadIdx.x - off] : 0;
        __syncthreads();
        sm[threadIdx.x] += y;
        __syncthreads();
    }
    partials[threadIdx.x] = sm[threadIdx.x] - x;     // exclusive chunk offsets
    if (threadIdx.x == 1023) partials[1024] = sm[1023];
}

// k4: scatter. deg doubles as countdown cursor: slot = (deg[d])-- - 1 in [0, degree).
// csr_src row base = lex[d] + par[d>>10]. Order within a row: arbitrary (fine).
__global__ void scatter_kernel(const int* __restrict__ src, const int* __restrict__ dst,
                               const int* __restrict__ lex, const int* __restrict__ par,
                               int* __restrict__ deg, int* __restrict__ csr_src, int E) {
    int stride = gridDim.x * blockDim.x;
    for (int e = blockIdx.x * blockDim.x + threadIdx.x; e < E; e += stride) {
        int d = dst[e];
        int slot = atomicSub(&deg[d], 1) - 1;
        int base = lex[d] + par[d >> 10];
        csr_src[base + slot] = src[e];
    }
}

// ---------------- per-layer kernels ----------------

// half-wave per node: s[v]=h.w_src, t[v]=h.w_dst, AND h -> fp16 copy (single read of h).
__global__ void stconv_kernel(const float* __restrict__ h, const float* __restrict__ att_w_l,
                              float* __restrict__ s, float* __restrict__ t,
                              __half* __restrict__ h16, int n) {
    int gid  = blockIdx.x * blockDim.x + threadIdx.x;
    int wid  = gid >> 6;
    int lane = threadIdx.x & 63;
    int half = lane >> 5;
    int hl   = lane & 31;
    int v    = wid * 2 + half;
    if (v >= n) return;
    float4 hv = ((const float4*)(h + (size_t)v * 128))[hl];
    __half2 p01 = __floats2half2_rn(hv.x, hv.y);
    __half2 p23 = __floats2half2_rn(hv.z, hv.w);
    float2 packed;
    packed.x = *(const float*)&p01;
    packed.y = *(const float*)&p23;
    ((float2*)(h16 + (size_t)v * 128))[hl] = packed;
    float4 ws = ((const float4*)att_w_l)[hl];
    float4 wd = ((const float4*)(att_w_l + 128))[hl];
    float ps = hv.x * ws.x + hv.y * ws.y + hv.z * ws.z + hv.w * ws.w;
    float pt = hv.x * wd.x + hv.y * wd.y + hv.z * wd.z + hv.w * wd.w;
    for (int off = 16; off > 0; off >>= 1) {
        ps += __shfl_down(ps, off);
        pt += __shfl_down(pt, off);
    }
    if (hl == 0) { s[v] = ps; t[v] = pt; }
}

// load one 8-dim fp16 block (16B) and accumulate (fp16 src, fp32 acc).
__device__ __forceinline__ void gath8(const __half* __restrict__ hin, int u, float w,
                                      int qlane, float acc[8]) {
    float4 r = ((const float4*)(hin + ((size_t)(unsigned)u << 7)))[qlane];
    const __half2* hp = (const __half2*)&r;
    #pragma unroll
    for (int d = 0; d < 4; ++d) {
        acc[2 * d]     = fmaf(__low2float(hp[d]),  w, acc[2 * d]);
        acc[2 * d + 1] = fmaf(__high2float(hp[d]), w, acc[2 * d + 1]);
    }
}

// one wave per node, single pass, EDGE-TILED (R1/R3 schedule: unroll 4, 32 VGPR, ~67% occ).
// beg/end reconstructed from lex+par (row_ptr array eliminated with the multisplit).
template<bool LAST>
__global__ __launch_bounds__(256, 8)
void agg_kernel(const __half* __restrict__ hin, const float* __restrict__ s,
                const float* __restrict__ t, const int* __restrict__ lex,
                const int* __restrict__ par, const int* __restrict__ csr_src,
                __half* __restrict__ hout16, float* __restrict__ outf,
                const float* __restrict__ att_w_next,
                float* __restrict__ s2, float* __restrict__ t2, int n) {
    int gid   = blockIdx.x * blockDim.x + threadIdx.x;
    int v     = gid >> 6;
    int lane  = threadIdx.x & 63;
    if (v >= n) return;
    int quad  = lane >> 4;        // which of 4 concurrent edges
    int qlane = lane & 15;        // dim block: dims [8*qlane, 8*qlane+8)

    int beg = lex[v]     + par[v >> 10];          // wave-uniform loads
    int end = lex[v + 1] + par[(v + 1) >> 10];
    float tv = t[v];

    float acc[8] = {0.f, 0.f, 0.f, 0.f, 0.f, 0.f, 0.f, 0.f};
    float lsum_l = 0.f;                        // per-lane partial of sum(exp)

    for (int base = beg; base < end; base += 64) {
        int cnt = end - base;                  // >= 1
        if (cnt > 64) cnt = 64;
        // step 1: per-lane edge metadata (one exp per EDGE)
        int idx = base + min(lane, cnt - 1);   // clamp keeps address valid; w=0 below
        int u   = csr_src[idx];
        float a = s[u] + tv;
        float e = (a > 0.f) ? a : NEG_SLOPE * a;
        float wl = (lane < cnt) ? __expf(e) : 0.f;
        lsum_l += wl;
        // step 2: gather, 4 edges per step, unroll 4 (16 edges / 4 loads in flight)
        int steps = (cnt + 3) >> 2;
        int k = 0;
        for (; k + 3 < steps; k += 4) {
            int sl0 = (k << 2) + quad;
            int   u0 = __shfl(u, sl0);       float w0 = __shfl(wl, sl0);
            int   u1 = __shfl(u, sl0 + 4);   float w1 = __shfl(wl, sl0 + 4);
            int   u2 = __shfl(u, sl0 + 8);   float w2 = __shfl(wl, sl0 + 8);
            int   u3 = __shfl(u, sl0 + 12);  float w3 = __shfl(wl, sl0 + 12);
            gath8(hin, u0, w0, qlane, acc);
            gath8(hin, u1, w1, qlane, acc);
            gath8(hin, u2, w2, qlane, acc);
            gath8(hin, u3, w3, qlane, acc);
        }
        for (; k < steps; ++k) {
            int sl = (k << 2) + quad;          // if sl >= cnt: w=0, u clamped-valid
            int   u0 = __shfl(u, sl);
            float w0 = __shfl(wl, sl);
            gath8(hin, u0, w0, qlane, acc);
        }
    }
    // fold the 4 quad partials: dim block qlane lives in lanes {q, q+16, q+32, q+48}
    #pragma unroll
    for (int j = 0; j < 8; ++j) {
        acc[j] += __shfl_xor(acc[j], 16);
        acc[j] += __shfl_xor(acc[j], 32);
    }
    float lsum = lsum_l;
    for (int off = 32; off > 0; off >>= 1) lsum += __shfl_xor(lsum, off);
    float inv_l = (lsum > 0.f) ? (1.0f / lsum) : 0.f;   // deg-0 -> zero row
    #pragma unroll
    for (int j = 0; j < 8; ++j) acc[j] *= inv_l;

    if (LAST) {
        if (quad == 0) {
            float4* op = (float4*)(outf + (size_t)v * 128);
            op[2 * qlane]     = make_float4(acc[0], acc[1], acc[2], acc[3]);
            op[2 * qlane + 1] = make_float4(acc[4], acc[5], acc[6], acc[7]);
        }
    } else {
        if (quad == 0) {
            __half2 p0 = __floats2half2_rn(acc[0], acc[1]);
            __half2 p1 = __floats2half2_rn(acc[2], acc[3]);
            __half2 p2 = __floats2half2_rn(acc[4], acc[5]);
            __half2 p3 = __floats2half2_rn(acc[6], acc[7]);
            int4 pk;
            pk.x = *(const int*)&p0; pk.y = *(const int*)&p1;
            pk.z = *(const int*)&p2; pk.w = *(const int*)&p3;
            ((int4*)(hout16 + (size_t)v * 128))[qlane] = pk;
        }
        // fused next-layer s/t: every lane computes its dim-block dot (all quads hold
        // the reduced acc), reduce over 16 lanes; lane 0 writes.
        float4 ws0 = ((const float4*)att_w_next)[2 * qlane];
        float4 ws1 = ((const float4*)att_w_next)[2 * qlane + 1];
        float4 wd0 = ((const float4*)(att_w_next + 128))[2 * qlane];
        float4 wd1 = ((const float4*)(att_w_next + 128))[2 * qlane + 1];
        float ps = acc[0] * ws0.x + acc[1] * ws0.y + acc[2] * ws0.z + acc[3] * ws0.w
                 + acc[4] * ws1.x + acc[5] * ws1.y + acc[6] * ws1.z + acc[7] * ws1.w;
        float pt = acc[0] * wd0.x + acc[1] * wd0.y + acc[2] * wd0.z + acc[3] * wd0.w
                 + acc[4] * wd1.x + acc[5] * wd1.y + acc[6] * wd1.z + acc[7] * wd1.w;
        for (int off = 8; off > 0; off >>= 1) {
            ps += __shfl_down(ps, off);
            pt += __shfl_down(pt, off);
        }
        if (lane == 0) { s2[v] = ps; t2[v] = pt; }
    }
}

// ---------------- launch ----------------

extern "C" void kernel_launch(void* const* d_in, const int* in_sizes, int n_in,
                              void* d_out, int out_size, void* d_ws, size_t ws_size,
                              hipStream_t stream) {
    const float* h0    = (const float*)d_in[0];
    const int*   src   = (const int*)d_in[1];
    const int*   dst   = (const int*)d_in[2];
    const float* att_w = (const float*)d_in[3];
    int N = in_sizes[0] / 128;
    int E = in_sizes[1];
    int L = in_sizes[3] / 256;
    float* out = (float*)d_out;

    int n1 = N + 1;                          // scan covers deg[0..N], deg[N]=0 pad
    int nch = (n1 + 1023) / 1024;            // 49 scan chunks (<=1024 required)

    char* ws = (char*)d_ws;
    size_t off = 0;
    auto alloc = [&](size_t bytes) -> void* {
        void* p = ws + off;
        off = (off + bytes + 511) & ~(size_t)511;
        return p;
    };
    int*      csr_src   = (int*)     alloc((size_t)E * 4);
    int*      deg       = (int*)     alloc((size_t)n1 * 4);
    int*      local_ex  = (int*)     alloc((size_t)n1 * 4);
    int*      partials  = (int*)     alloc(1025 * 4);
    float*    s1        = (float*)   alloc((size_t)N * 4);
    float*    t1        = (float*)   alloc((size_t)N * 4);
    float*    s2        = (float*)   alloc((size_t)N * 4);
    float*    t2        = (float*)   alloc((size_t)N * 4);
    __half*   hA        = (__half*)  alloc((size_t)N * 128 * 2);
    __half*   hB        = (__half*)  alloc((size_t)N * 128 * 2);

    hipMemsetAsync(deg, 0, (size_t)n1 * 4, stream);
    deghist_kernel<<<2048, 256, 0, stream>>>(dst, deg, E);
    scan1_kernel<<<nch, 1024, 0, stream>>>(deg, local_ex, partials, n1);
    scan2_kernel<<<1, 1024, 0, stream>>>(partials, nch);
    scatter_kernel<<<2048, 256, 0, stream>>>(src, dst, local_ex, partials, deg, csr_src, E);

    const int tb = 256;
    int node_blocks = (N * 64 + tb - 1) / tb;        // one wave per node (agg)
    int st_blocks   = ((N + 1) / 2 * 64 + tb - 1) / tb;  // half-wave per node (stconv)

    // layer 0 s/t + fp16 conversion (single pass over h0)
    stconv_kernel<<<st_blocks, tb, 0, stream>>>(h0, att_w, s1, t1, hA, N);

    __half* hin = hA;
    __half* hnx = hB;
    float *sc = s1, *tc = t1, *sn = s2, *tn = t2;
    for (int l = 0; l < L; ++l) {
        if (l == L - 1) {
            agg_kernel<true><<<node_blocks, tb, 0, stream>>>(
                hin, sc, tc, local_ex, partials, csr_src,
                nullptr, out, nullptr, nullptr, nullptr, N);
        } else {
            agg_kernel<false><<<node_blocks, tb, 0, stream>>>(
                hin, sc, tc, local_ex, partials, csr_src,
                hnx, nullptr, att_w + (size_t)(l + 1) * 256, sn, tn, N);
            __half* tmp = hin; hin = hnx; hnx = tmp;
            float* tf;
            tf = sc; sc = sn; sn = tf;
            tf = tc; tc = tn; tn = tf;
        }
    }
}

// Round 5
// 214.887 us; speedup vs baseline: 1.5973x; 1.5973x over previous
//
#include <hip/hip_runtime.h>
#include <hip/hip_fp16.h>
#include <math.h>

#define NEG_SLOPE 0.01f
#define BKT_BITS 7        // 128 nodes per bucket
#define BKT_MASK 127
#define SBLOCKS  256      // blocks in the multisplit phases
#define STPB     512      // threads per multisplit block

// ---------------- bucketed CSR build (R3-proven; R4 counting sort REGRESSED:
// scattered 4B writes -> 64B line writebacks, WRITE_SIZE 103MB, 95us) ----------------

// Fused S1 + stconv: blocks [0,SBLOCKS) build the per-(block,bucket) histogram of
// dst>>7 (int4-vectorized edge reads); blocks [SBLOCKS, ...) do the independent
// stconv work (s/t projections + fp16 conversion). Saves a launch boundary and
// overlaps atomic-bound and BW-bound work.
__global__ void build_st_kernel(const int* __restrict__ dst, int* __restrict__ blockhist,
                                int E, int NB, int nq, int qchunk,
                                const float* __restrict__ h, const float* __restrict__ att_w_l,
                                float* __restrict__ s, float* __restrict__ t,
                                __half* __restrict__ h16, int N) {
    extern __shared__ int lh[];
    if (blockIdx.x < SBLOCKS) {
        for (int k = threadIdx.x; k < NB; k += blockDim.x) lh[k] = 0;
        __syncthreads();
        int b = blockIdx.x;
        int qbeg = b * qchunk, qend = min(nq, qbeg + qchunk);
        for (int q = qbeg + (int)threadIdx.x; q < qend; q += blockDim.x) {
            int e = q << 2;
            if (e + 3 < E) {
                int4 d4 = *(const int4*)(dst + e);
                atomicAdd(&lh[d4.x >> BKT_BITS], 1);
                atomicAdd(&lh[d4.y >> BKT_BITS], 1);
                atomicAdd(&lh[d4.z >> BKT_BITS], 1);
                atomicAdd(&lh[d4.w >> BKT_BITS], 1);
            } else {
                for (int j = e; j < E; ++j) atomicAdd(&lh[dst[j] >> BKT_BITS], 1);
            }
        }
        __syncthreads();
        for (int k = threadIdx.x; k < NB; k += blockDim.x)
            blockhist[k * SBLOCKS + blockIdx.x] = lh[k];
    } else {
        // stconv: half-wave per node; 512 thr -> 16 nodes/block
        int sb  = blockIdx.x - SBLOCKS;
        int gid = sb * (int)blockDim.x + threadIdx.x;
        int wid = gid >> 6;
        int lane = threadIdx.x & 63;
        int half = lane >> 5;
        int hl   = lane & 31;
        int v    = wid * 2 + half;
        if (v >= N) return;
        float4 hv = ((const float4*)(h + (size_t)v * 128))[hl];
        __half2 p01 = __floats2half2_rn(hv.x, hv.y);
        __half2 p23 = __floats2half2_rn(hv.z, hv.w);
        float2 packed;
        packed.x = *(const float*)&p01;
        packed.y = *(const float*)&p23;
        ((float2*)(h16 + (size_t)v * 128))[hl] = packed;
        float4 ws = ((const float4*)att_w_l)[hl];
        float4 wd = ((const float4*)(att_w_l + 128))[hl];
        float ps = hv.x * ws.x + hv.y * ws.y + hv.z * ws.z + hv.w * ws.w;
        float pt = hv.x * wd.x + hv.y * wd.y + hv.z * wd.z + hv.w * wd.w;
        for (int off = 16; off > 0; off >>= 1) {
            ps += __shfl_down(ps, off);
            pt += __shfl_down(pt, off);
        }
        if (hl == 0) { s[v] = ps; t[v] = pt; }
    }
}

// multi-block scan (round-4 proven; single-block fused scan was a 77us regression)
__global__ void scan1_kernel(const int* __restrict__ in, int* __restrict__ local_excl,
                             int* __restrict__ partials, int n) {
    __shared__ int sm[1024];
    int i = blockIdx.x * 1024 + threadIdx.x;
    int x = (i < n) ? in[i] : 0;
    sm[threadIdx.x] = x;
    __syncthreads();
    for (int off = 1; off < 1024; off <<= 1) {
        int y = (threadIdx.x >= (unsigned)off) ? sm[threadIdx.x - off] : 0;
        __syncthreads();
        sm[threadIdx.x] += y;
        __syncthreads();
    }
    if (i < n) local_excl[i] = sm[threadIdx.x] - x;
    if (threadIdx.x == 1023) partials[blockIdx.x] = sm[1023];
}

__global__ void scan2_kernel(int* __restrict__ partials, int nchunks) {
    __shared__ int sm[1024];
    int x = (threadIdx.x < (unsigned)nchunks) ? partials[threadIdx.x] : 0;
    sm[threadIdx.x] = x;
    __syncthreads();
    for (int off = 1; off < 1024; off <<= 1) {
        int y = (threadIdx.x >= (unsigned)off) ? sm[threadIdx.x - off] : 0;
        __syncthreads();
        sm[threadIdx.x] += y;
        __syncthreads();
    }
    partials[threadIdx.x] = sm[threadIdx.x] - x;     // exclusive chunk offsets
    if (threadIdx.x == 1023) partials[1024] = sm[1023];
}

// scan3 ELIMINATED: consumers reconstruct bh_scan[i] = local_excl[i] + partials[i>>10]
__device__ __forceinline__ int bh_at(const int* __restrict__ local_ex,
                                     const int* __restrict__ partials, int i) {
    return local_ex[i] + partials[i >> 10];
}

// S3: multisplit — packed (src<<7)|(dst&127) into per-(block,bucket) segments.
// int4-vectorized edge reads; same quad->block mapping as the histogram phase.
__global__ void bksplit_kernel(const int* __restrict__ src, const int* __restrict__ dst,
                               const int* __restrict__ local_ex, const int* __restrict__ partials,
                               unsigned* __restrict__ pairs,
                               int E, int NB, int nq, int qchunk) {
    extern __shared__ int lm[];                // lbase[NB] then lcnt[NB]
    int* lbase = lm;
    int* lcnt  = lm + NB;
    int b = blockIdx.x;
    for (int k = threadIdx.x; k < NB; k += blockDim.x) {
        lbase[k] = bh_at(local_ex, partials, k * SBLOCKS + b);
        lcnt[k]  = 0;
    }
    __syncthreads();
    int qbeg = b * qchunk, qend = min(nq, qbeg + qchunk);
    for (int q = qbeg + (int)threadIdx.x; q < qend; q += blockDim.x) {
        int e = q << 2;
        if (e + 3 < E) {
            int4 d4 = *(const int4*)(dst + e);
            int4 s4 = *(const int4*)(src + e);
            int k0 = d4.x >> BKT_BITS;
            int p0 = lbase[k0] + atomicAdd(&lcnt[k0], 1);
            pairs[p0] = ((unsigned)s4.x << BKT_BITS) | (unsigned)(d4.x & BKT_MASK);
            int k1 = d4.y >> BKT_BITS;
            int p1 = lbase[k1] + atomicAdd(&lcnt[k1], 1);
            pairs[p1] = ((unsigned)s4.y << BKT_BITS) | (unsigned)(d4.y & BKT_MASK);
            int k2 = d4.z >> BKT_BITS;
            int p2 = lbase[k2] + atomicAdd(&lcnt[k2], 1);
            pairs[p2] = ((unsigned)s4.z << BKT_BITS) | (unsigned)(d4.z & BKT_MASK);
            int k3 = d4.w >> BKT_BITS;
            int p3 = lbase[k3] + atomicAdd(&lcnt[k3], 1);
            pairs[p3] = ((unsigned)s4.w << BKT_BITS) | (unsigned)(d4.w & BKT_MASK);
        } else {
            for (int j = e; j < E; ++j) {
                int d = dst[j];
                int k = d >> BKT_BITS;
                int pos = lbase[k] + atomicAdd(&lcnt[k], 1);
                pairs[pos] = ((unsigned)src[j] << BKT_BITS) | (unsigned)(d & BKT_MASK);
            }
        }
    }
}

// S4: one block per bucket — per-node degrees + LDS scan -> row_ptr, then local CSR scatter.
__global__ void csr_build_kernel(const unsigned* __restrict__ pairs,
                                 const int* __restrict__ local_ex, const int* __restrict__ partials,
                                 int* __restrict__ row_ptr, int* __restrict__ csr_src,
                                 int E, int N, int NB) {
    __shared__ int ldeg[128];
    __shared__ int lscan[128];
    __shared__ int lpos[128];
    int k = blockIdx.x;
    int bbase = bh_at(local_ex, partials, k * SBLOCKS);
    int bend  = (k == NB - 1) ? E : bh_at(local_ex, partials, (k + 1) * SBLOCKS);
    if (threadIdx.x < 128) ldeg[threadIdx.x] = 0;
    __syncthreads();
    for (int i = bbase + (int)threadIdx.x; i < bend; i += blockDim.x)
        atomicAdd(&ldeg[pairs[i] & BKT_MASK], 1);
    __syncthreads();
    int x = (threadIdx.x < 128) ? ldeg[threadIdx.x] : 0;
    if (threadIdx.x < 128) lscan[threadIdx.x] = x;
    __syncthreads();
    for (int off = 1; off < 128; off <<= 1) {
        int y = 0;
        if (threadIdx.x < 128 && threadIdx.x >= (unsigned)off) y = lscan[threadIdx.x - off];
        __syncthreads();
        if (threadIdx.x < 128) lscan[threadIdx.x] += y;
        __syncthreads();
    }
    if (threadIdx.x < 128) {
        int excl = lscan[threadIdx.x] - x;
        int node = (k << BKT_BITS) + threadIdx.x;
        if (node < N) row_ptr[node] = bbase + excl;
        lpos[threadIdx.x] = excl;
    }
    if (k == NB - 1 && threadIdx.x == 0) row_ptr[N] = E;
    __syncthreads();
    for (int i = bbase + (int)threadIdx.x; i < bend; i += blockDim.x) {
        unsigned p = pairs[i];
        int pos = atomicAdd(&lpos[p & BKT_MASK], 1);
        csr_src[bbase + pos] = (int)(p >> BKT_BITS);
    }
}

// ---------------- aggregation ----------------

// load one 8-dim fp16 block (16B) and accumulate (fp16 src via v_fma_mix, fp32 acc).
__device__ __forceinline__ void gath8(const __half* __restrict__ hin, int u, float w,
                                      int qlane, float acc[8]) {
    float4 r = ((const float4*)(hin + ((size_t)(unsigned)u << 7)))[qlane];
    const __half2* hp = (const __half2*)&r;
    #pragma unroll
    for (int d = 0; d < 4; ++d) {
        acc[2 * d]     = fmaf(__low2float(hp[d]),  w, acc[2 * d]);
        acc[2 * d + 1] = fmaf(__high2float(hp[d]), w, acc[2 * d + 1]);
    }
}

// one wave per node, single pass, EDGE-TILED (R1/R3 schedule: unroll 4, 32 VGPR, ~67% occ).
template<bool LAST>
__global__ __launch_bounds__(256, 8)
void agg_kernel(const __half* __restrict__ hin, const float* __restrict__ s,
                const float* __restrict__ t, const int* __restrict__ row_ptr,
                const int* __restrict__ csr_src,
                __half* __restrict__ hout16, float* __restrict__ outf,
                const float* __restrict__ att_w_next,
                float* __restrict__ s2, float* __restrict__ t2, int n) {
    int gid   = blockIdx.x * blockDim.x + threadIdx.x;
    int v     = gid >> 6;
    int lane  = threadIdx.x & 63;
    if (v >= n) return;
    int quad  = lane >> 4;        // which of 4 concurrent edges
    int qlane = lane & 15;        // dim block: dims [8*qlane, 8*qlane+8)

    int beg = row_ptr[v];
    int end = row_ptr[v + 1];
    float tv = t[v];

    float acc[8] = {0.f, 0.f, 0.f, 0.f, 0.f, 0.f, 0.f, 0.f};
    float lsum_l = 0.f;                        // per-lane partial of sum(exp)

    for (int base = beg; base < end; base += 64) {
        int cnt = end - base;                  // >= 1
        if (cnt > 64) cnt = 64;
        // step 1: per-lane edge metadata (one exp per EDGE)
        int idx = base + min(lane, cnt - 1);   // clamp keeps address valid; w=0 below
        int u   = csr_src[idx];
        float a = s[u] + tv;
        float e = (a > 0.f) ? a : NEG_SLOPE * a;
        float wl = (lane < cnt) ? __expf(e) : 0.f;
        lsum_l += wl;
        // step 2: gather, 4 edges per step, unroll 4 (16 edges / 4 loads in flight)
        int steps = (cnt + 3) >> 2;
        int k = 0;
        for (; k + 3 < steps; k += 4) {
            int sl0 = (k << 2) + quad;
            int   u0 = __shfl(u, sl0);       float w0 = __shfl(wl, sl0);
            int   u1 = __shfl(u, sl0 + 4);   float w1 = __shfl(wl, sl0 + 4);
            int   u2 = __shfl(u, sl0 + 8);   float w2 = __shfl(wl, sl0 + 8);
            int   u3 = __shfl(u, sl0 + 12);  float w3 = __shfl(wl, sl0 + 12);
            gath8(hin, u0, w0, qlane, acc);
            gath8(hin, u1, w1, qlane, acc);
            gath8(hin, u2, w2, qlane, acc);
            gath8(hin, u3, w3, qlane, acc);
        }
        for (; k < steps; ++k) {
            int sl = (k << 2) + quad;          // if sl >= cnt: w=0, u clamped-valid
            int   u0 = __shfl(u, sl);
            float w0 = __shfl(wl, sl);
            gath8(hin, u0, w0, qlane, acc);
        }
    }
    // fold the 4 quad partials: dim block qlane lives in lanes {q, q+16, q+32, q+48}
    #pragma unroll
    for (int j = 0; j < 8; ++j) {
        acc[j] += __shfl_xor(acc[j], 16);
        acc[j] += __shfl_xor(acc[j], 32);
    }
    float lsum = lsum_l;
    for (int off = 32; off > 0; off >>= 1) lsum += __shfl_xor(lsum, off);
    float inv_l = (lsum > 0.f) ? (1.0f / lsum) : 0.f;   // deg-0 -> zero row
    #pragma unroll
    for (int j = 0; j < 8; ++j) acc[j] *= inv_l;

    if (LAST) {
        if (quad == 0) {
            float4* op = (float4*)(outf + (size_t)v * 128);
            op[2 * qlane]     = make_float4(acc[0], acc[1], acc[2], acc[3]);
            op[2 * qlane + 1] = make_float4(acc[4], acc[5], acc[6], acc[7]);
        }
    } else {
        if (quad == 0) {
            __half2 p0 = __floats2half2_rn(acc[0], acc[1]);
            __half2 p1 = __floats2half2_rn(acc[2], acc[3]);
            __half2 p2 = __floats2half2_rn(acc[4], acc[5]);
            __half2 p3 = __floats2half2_rn(acc[6], acc[7]);
            int4 pk;
            pk.x = *(const int*)&p0; pk.y = *(const int*)&p1;
            pk.z = *(const int*)&p2; pk.w = *(const int*)&p3;
            ((int4*)(hout16 + (size_t)v * 128))[qlane] = pk;
        }
        // fused next-layer s/t: every lane computes its dim-block dot (all quads hold
        // the reduced acc), reduce over 16 lanes; lane 0 writes.
        float4 ws0 = ((const float4*)att_w_next)[2 * qlane];
        float4 ws1 = ((const float4*)att_w_next)[2 * qlane + 1];
        float4 wd0 = ((const float4*)(att_w_next + 128))[2 * qlane];
        float4 wd1 = ((const float4*)(att_w_next + 128))[2 * qlane + 1];
        float ps = acc[0] * ws0.x + acc[1] * ws0.y + acc[2] * ws0.z + acc[3] * ws0.w
                 + acc[4] * ws1.x + acc[5] * ws1.y + acc[6] * ws1.z + acc[7] * ws1.w;
        float pt = acc[0] * wd0.x + acc[1] * wd0.y + acc[2] * wd0.z + acc[3] * wd0.w
                 + acc[4] * wd1.x + acc[5] * wd1.y + acc[6] * wd1.z + acc[7] * wd1.w;
        for (int off = 8; off > 0; off >>= 1) {
            ps += __shfl_down(ps, off);
            pt += __shfl_down(pt, off);
        }
        if (lane == 0) { s2[v] = ps; t2[v] = pt; }
    }
}

// ---------------- launch ----------------

extern "C" void kernel_launch(void* const* d_in, const int* in_sizes, int n_in,
                              void* d_out, int out_size, void* d_ws, size_t ws_size,
                              hipStream_t stream) {
    const float* h0    = (const float*)d_in[0];
    const int*   src   = (const int*)d_in[1];
    const int*   dst   = (const int*)d_in[2];
    const float* att_w = (const float*)d_in[3];
    int N = in_sizes[0] / 128;
    int E = in_sizes[1];
    int L = in_sizes[3] / 256;
    float* out = (float*)d_out;

    int NB = (N + BKT_MASK) >> BKT_BITS;     // 391 buckets
    int n2 = NB * SBLOCKS;                   // 100096 count-matrix entries
    int nq = (E + 3) >> 2;                   // edge quads (int4 units)
    int qchunk = (nq + SBLOCKS - 1) / SBLOCKS;
    int nch2 = (n2 + 1023) / 1024;           // 98 scan chunks (<=1024 required)

    char* ws = (char*)d_ws;
    size_t off = 0;
    auto alloc = [&](size_t bytes) -> void* {
        void* p = ws + off;
        off = (off + bytes + 511) & ~(size_t)511;
        return p;
    };
    int*      row_ptr   = (int*)     alloc((size_t)(N + 1) * 4);
    int*      csr_src   = (int*)     alloc((size_t)E * 4);
    float*    s1        = (float*)   alloc((size_t)N * 4);
    float*    t1        = (float*)   alloc((size_t)N * 4);
    float*    s2        = (float*)   alloc((size_t)N * 4);
    float*    t2        = (float*)   alloc((size_t)N * 4);
    __half*   hA        = (__half*)  alloc((size_t)N * 128 * 2);
    __half*   hB        = (__half*)  alloc((size_t)N * 128 * 2);
    unsigned* pairs     = (unsigned*)alloc((size_t)E * 4);
    int*      blockhist = (int*)     alloc((size_t)n2 * 4);
    int*      local_ex  = (int*)     alloc((size_t)n2 * 4);
    int*      partials  = (int*)     alloc(1025 * 4);

    // fused: histogram (blocks 0..SBLOCKS) + stconv (rest); stconv @512thr = 16 nodes/blk
    int st_blocks = ((N + 1) / 2 + 7) / 8;
    build_st_kernel<<<SBLOCKS + st_blocks, STPB, NB * 4, stream>>>(
        dst, blockhist, E, NB, nq, qchunk, h0, att_w, s1, t1, hA, N);
    scan1_kernel<<<nch2, 1024, 0, stream>>>(blockhist, local_ex, partials, n2);
    scan2_kernel<<<1, 1024, 0, stream>>>(partials, nch2);
    bksplit_kernel<<<SBLOCKS, STPB, 2 * NB * 4, stream>>>(src, dst, local_ex, partials,
                                                          pairs, E, NB, nq, qchunk);
    csr_build_kernel<<<NB, 512, 0, stream>>>(pairs, local_ex, partials,
                                             row_ptr, csr_src, E, N, NB);

    const int tb = 256;
    int node_blocks = (N * 64 + tb - 1) / tb;        // one wave per node (agg)

    __half* hin = hA;
    __half* hnx = hB;
    float *sc = s1, *tc = t1, *sn = s2, *tn = t2;
    for (int l = 0; l < L; ++l) {
        if (l == L - 1) {
            agg_kernel<true><<<node_blocks, tb, 0, stream>>>(
                hin, sc, tc, row_ptr, csr_src, nullptr, out, nullptr, nullptr, nullptr, N);
        } else {
            agg_kernel<false><<<node_blocks, tb, 0, stream>>>(
                hin, sc, tc, row_ptr, csr_src, hnx, nullptr,
                att_w + (size_t)(l + 1) * 256, sn, tn, N);
            __half* tmp = hin; hin = hnx; hnx = tmp;
            float* tf;
            tf = sc; sc = sn; sn = tf;
            tf = tc; tc = tn; tn = tf;
        }
    }
}